// Round 1
// baseline (1106.400 us; speedup 1.0000x reference)
//
#include <hip/hip_runtime.h>
#include <hip/hip_bf16.h>

typedef __bf16 bf16x8 __attribute__((ext_vector_type(8)));
typedef __bf16 bf16x4 __attribute__((ext_vector_type(4)));
typedef float  f32x4  __attribute__((ext_vector_type(4)));

#define DIM   1024
#define BSZ   4
#define LSEQ  8192
#define M_TOT (BSZ*LSEQ)      /* 32768 rows */
#define CHUNKS 64
#define CLEN  (LSEQ/CHUNKS)   /* 128 */

__device__ __forceinline__ float sigmoid_f(float z){ return 1.0f/(1.0f + __expf(-z)); }
__device__ __forceinline__ float tanh_f(float z){ return 1.0f - 2.0f/(__expf(2.0f*z) + 1.0f); }

// ---------------- prepass: x (fp32) -> x_hi, x_lo (bf16 split) ----------------
__global__ __launch_bounds__(256) void k_convert_x(const float* __restrict__ x,
                                                   __bf16* __restrict__ xh,
                                                   __bf16* __restrict__ xl){
    int i = (blockIdx.x*256 + threadIdx.x)*4;
    float4 v = *(const float4*)(x + i);
    float vv[4] = {v.x, v.y, v.z, v.w};
    bf16x4 h, l;
#pragma unroll
    for(int j=0;j<4;j++){
        __bf16 hj = (__bf16)vv[j];
        h[j] = hj;
        l[j] = (__bf16)(vv[j] - (float)hj);
    }
    *(bf16x4*)(xh + i) = h;
    *(bf16x4*)(xl + i) = l;
}

// ---------------- prepass: W (fp32, [k][n]) -> WT (bf16, [n][k]) ----------------
__global__ __launch_bounds__(256) void k_convert_w(const float* __restrict__ W,
                                                   __bf16* __restrict__ WT){
    __shared__ float t[32][33];
    int tx = threadIdx.x, ty = threadIdx.y;          // block (32,8)
    int n0 = blockIdx.x*32, k0 = blockIdx.y*32;
#pragma unroll
    for(int j=0;j<4;j++)
        t[ty + j*8][tx] = W[(size_t)(k0 + ty + j*8)*DIM + n0 + tx];
    __syncthreads();
#pragma unroll
    for(int j=0;j<4;j++)
        WT[(size_t)(n0 + ty + j*8)*DIM + k0 + tx] = (__bf16)t[tx][ty + j*8];
}

// ---------------- GEMM: z = (xh+xl) @ W + b, fused gate activation ----------------
// gates: 0=f (sigmoid->F), 1=i (tanh->INP), 2=ig (INP *= sigmoid), 3=og (sigmoid->G)
// launch A (launch_b=0): grid.x=24 covers gates {0,1,3}; launch B: grid.x=8, gate 2.
__global__ __launch_bounds__(256,2) void k_gemm(
        const __bf16* __restrict__ xh, const __bf16* __restrict__ xl,
        const __bf16* __restrict__ WT,            // [4][DIM][DIM], n-major
        const float* __restrict__ b0, const float* __restrict__ b1,
        const float* __restrict__ b2, const float* __restrict__ b3,
        float* __restrict__ F, float* __restrict__ INP, float* __restrict__ G,
        int launch_b)
{
    __shared__ __bf16 smem[3*128*32];   // A_hi | A_lo | B  (8 KiB each)
    const int tid = threadIdx.x;
    const int bx = blockIdx.x, mb = blockIdx.y;
    int gate, nb;
    if(launch_b){ gate = 2; nb = bx; }
    else { int gs = bx>>3; gate = (gs==2)?3:gs; nb = bx&7; }

    const __bf16* wt = WT + (size_t)gate*DIM*DIM + (size_t)nb*128*DIM;
    const __bf16* ah = xh + (size_t)mb*128*DIM;
    const __bf16* al = xl + (size_t)mb*128*DIM;

    const int lane = tid & 63, wv = tid >> 6;
    const int wm = wv & 1, wn = wv >> 1;          // 2x2 wave grid, 64x64 per wave
    const int quad = lane >> 4, l15 = lane & 15;

    f32x4 acc[4][4];
#pragma unroll
    for(int a=0;a<4;a++)
#pragma unroll
        for(int b=0;b<4;b++) acc[a][b] = (f32x4){0.f,0.f,0.f,0.f};

    const int rA  = tid >> 2;   // 0..63: row within half-tile
    const int seg = tid & 3;    // 16B segment within 64B row
    char* lds_base = (char*)smem;

#pragma unroll 1
    for(int kt=0; kt<DIM/32; ++kt){
        const int k0 = kt*32;
        __syncthreads();
        {
            const __bf16* g0 = ah + (size_t)(rA     )*DIM + k0 + seg*8;
            const __bf16* g1 = ah + (size_t)(64 + rA)*DIM + k0 + seg*8;
            const __bf16* g2 = al + (size_t)(rA     )*DIM + k0 + seg*8;
            const __bf16* g3 = al + (size_t)(64 + rA)*DIM + k0 + seg*8;
            const __bf16* g4 = wt + (size_t)(rA     )*DIM + k0 + seg*8;
            const __bf16* g5 = wt + (size_t)(64 + rA)*DIM + k0 + seg*8;
            __builtin_amdgcn_global_load_lds((const __attribute__((address_space(1))) void*)g0,
                (__attribute__((address_space(3))) void*)(lds_base + (0*256+tid)*16), 16, 0, 0);
            __builtin_amdgcn_global_load_lds((const __attribute__((address_space(1))) void*)g1,
                (__attribute__((address_space(3))) void*)(lds_base + (1*256+tid)*16), 16, 0, 0);
            __builtin_amdgcn_global_load_lds((const __attribute__((address_space(1))) void*)g2,
                (__attribute__((address_space(3))) void*)(lds_base + (2*256+tid)*16), 16, 0, 0);
            __builtin_amdgcn_global_load_lds((const __attribute__((address_space(1))) void*)g3,
                (__attribute__((address_space(3))) void*)(lds_base + (3*256+tid)*16), 16, 0, 0);
            __builtin_amdgcn_global_load_lds((const __attribute__((address_space(1))) void*)g4,
                (__attribute__((address_space(3))) void*)(lds_base + (4*256+tid)*16), 16, 0, 0);
            __builtin_amdgcn_global_load_lds((const __attribute__((address_space(1))) void*)g5,
                (__attribute__((address_space(3))) void*)(lds_base + (5*256+tid)*16), 16, 0, 0);
        }
        __syncthreads();

        bf16x8 fa[4], fl[4], fb[4];
#pragma unroll
        for(int i=0;i<4;i++){
            int row  = wm*64 + i*16 + l15;
            int nrow = wn*64 + i*16 + l15;
            fa[i] = *(const bf16x8*)(smem +        row*32  + quad*8);
            fl[i] = *(const bf16x8*)(smem + 4096 + row*32  + quad*8);
            fb[i] = *(const bf16x8*)(smem + 8192 + nrow*32 + quad*8);
        }
#pragma unroll
        for(int i=0;i<4;i++)
#pragma unroll
            for(int j=0;j<4;j++){
                acc[i][j] = __builtin_amdgcn_mfma_f32_16x16x32_bf16(fa[i], fb[j], acc[i][j], 0,0,0);
                acc[i][j] = __builtin_amdgcn_mfma_f32_16x16x32_bf16(fl[i], fb[j], acc[i][j], 0,0,0);
            }
    }

    const float* bias = (gate==0)? b0 : (gate==1)? b1 : (gate==2)? b2 : b3;
#pragma unroll
    for(int i=0;i<4;i++){
#pragma unroll
        for(int j=0;j<4;j++){
            int col = nb*128 + wn*64 + j*16 + l15;
            float bv = bias[col];
#pragma unroll
            for(int r=0;r<4;r++){
                int m = mb*128 + wm*64 + i*16 + quad*4 + r;
                size_t o = (size_t)m*DIM + col;
                float z = acc[i][j][r] + bv;
                if(gate==0)      F[o]   = sigmoid_f(z);
                else if(gate==1) INP[o] = tanh_f(z);
                else if(gate==2) INP[o] = INP[o]*sigmoid_f(z);
                else             G[o]   = sigmoid_f(z);
            }
        }
    }
}

// ---------------- scan pass 1: per-chunk (P = prod f, H = local scan from 0) ----------------
__global__ __launch_bounds__(256) void k_scan1(const float* __restrict__ F, const float* __restrict__ INP,
                                               float* __restrict__ P, float* __restrict__ Hc){
    int c = blockIdx.x, dblk = blockIdx.y, b = blockIdx.z;
    int d = dblk*256 + threadIdx.x;
    size_t base = ((size_t)(b*LSEQ + c*CLEN))*DIM + d;
    float p = 1.0f, h = 0.0f;
#pragma unroll 4
    for(int t=0;t<CLEN;t++){
        float f = F[base + (size_t)t*DIM];
        float i = INP[base + (size_t)t*DIM];
        h = f*h + i;
        p *= f;
    }
    int bd = b*DIM + d;
    P [c*(BSZ*DIM) + bd] = p;
    Hc[c*(BSZ*DIM) + bd] = h;
}

// ---------------- scan pass 2: chunk-level scan, seeded with last_hidden_init ----------------
__global__ __launch_bounds__(256) void k_scan2(const float* __restrict__ P, const float* __restrict__ Hc,
                                               const float* __restrict__ lh, float* __restrict__ Hin){
    int bd = blockIdx.x*256 + threadIdx.x;   // 0..4095
    int d = bd & (DIM-1);
    float h = lh[d];
#pragma unroll
    for(int c=0;c<CHUNKS;c++){
        Hin[c*(BSZ*DIM) + bd] = h;
        h = P[c*(BSZ*DIM) + bd]*h + Hc[c*(BSZ*DIM) + bd];
    }
}

// ---------------- scan pass 3: replay chunks with h_in, fuse y = tanh(h)*G ----------------
__global__ __launch_bounds__(256) void k_scan3(const float* __restrict__ F, const float* __restrict__ INP,
                                               const float* __restrict__ Hin, float* __restrict__ Y){
    int c = blockIdx.x, dblk = blockIdx.y, b = blockIdx.z;
    int d = dblk*256 + threadIdx.x;
    int bd = b*DIM + d;
    size_t base = ((size_t)(b*LSEQ + c*CLEN))*DIM + d;
    float h = Hin[c*(BSZ*DIM) + bd];
#pragma unroll 4
    for(int t=0;t<CLEN;t++){
        size_t o = base + (size_t)t*DIM;
        float f = F[o], i = INP[o];
        h = f*h + i;
        Y[o] = tanh_f(h)*Y[o];    // Y currently holds sigmoid(z_og)
    }
}

extern "C" void kernel_launch(void* const* d_in, const int* in_sizes, int n_in,
                              void* d_out, int out_size, void* d_ws, size_t ws_size,
                              hipStream_t stream){
    const float* x  = (const float*)d_in[0];
    const float* W[4]    = {(const float*)d_in[1], (const float*)d_in[3],
                            (const float*)d_in[5], (const float*)d_in[7]};
    const float* bias[4] = {(const float*)d_in[2], (const float*)d_in[4],
                            (const float*)d_in[6], (const float*)d_in[8]};
    const float* lh = (const float*)d_in[9];
    float* Y = (float*)d_out;

    char* ws = (char*)d_ws;
    __bf16* xh = (__bf16*)(ws);                         //  64 MiB
    __bf16* xl = (__bf16*)(ws + ((size_t) 64<<20));     //  64 MiB
    __bf16* WT = (__bf16*)(ws + ((size_t)128<<20));     //   8 MiB
    float*  F  = (float*) (ws + ((size_t)136<<20));     // 128 MiB
    float*  INP= (float*) (ws + ((size_t)264<<20));     // 128 MiB
    float*  P  = (float*) (ws + ((size_t)392<<20));     //   1 MiB
    float*  Hc = (float*) (ws + ((size_t)393<<20));     //   1 MiB
    float*  Hin= (float*) (ws + ((size_t)394<<20));     //   1 MiB  (total 395 MiB)

    hipLaunchKernelGGL(k_convert_x, dim3(M_TOT*DIM/(4*256)), dim3(256), 0, stream, x, xh, xl);
    for(int g=0; g<4; ++g)
        hipLaunchKernelGGL(k_convert_w, dim3(32,32), dim3(32,8), 0, stream,
                           W[g], WT + (size_t)g*DIM*DIM);
    hipLaunchKernelGGL(k_gemm, dim3(24, M_TOT/128), dim3(256), 0, stream,
                       xh, xl, WT, bias[0], bias[1], bias[2], bias[3], F, INP, Y, 0);
    hipLaunchKernelGGL(k_gemm, dim3(8, M_TOT/128), dim3(256), 0, stream,
                       xh, xl, WT, bias[0], bias[1], bias[2], bias[3], F, INP, Y, 1);
    hipLaunchKernelGGL(k_scan1, dim3(CHUNKS, DIM/256, BSZ), dim3(256), 0, stream, F, INP, P, Hc);
    hipLaunchKernelGGL(k_scan2, dim3(BSZ*DIM/256), dim3(256), 0, stream, P, Hc, lh, Hin);
    hipLaunchKernelGGL(k_scan3, dim3(CHUNKS, DIM/256, BSZ), dim3(256), 0, stream, F, INP, Hin, Y);
}

// Round 3
// 814.655 us; speedup vs baseline: 1.3581x; 1.3581x over previous
//
#include <hip/hip_runtime.h>
#include <hip/hip_bf16.h>

typedef __bf16 bf16x8 __attribute__((ext_vector_type(8)));
typedef __bf16 bf16x4 __attribute__((ext_vector_type(4)));
typedef __bf16 bf16x2 __attribute__((ext_vector_type(2)));
typedef float  f32x4  __attribute__((ext_vector_type(4)));

#define DIM   1024
#define BSZ   4
#define LSEQ  8192
#define M_TOT (BSZ*LSEQ)      /* 32768 rows */
#define CHUNKS 64
#define CLEN  (LSEQ/CHUNKS)   /* 128 */

__device__ __forceinline__ float sigmoid_f(float z){ return 1.0f/(1.0f + __expf(-z)); }
__device__ __forceinline__ float tanh_f(float z){ return 1.0f - 2.0f/(__expf(2.0f*z) + 1.0f); }

// ---------------- prepass: x (fp32) -> x_hi, x_lo (bf16 split) ----------------
__global__ __launch_bounds__(256) void k_convert_x(const float* __restrict__ x,
                                                   __bf16* __restrict__ xh,
                                                   __bf16* __restrict__ xl){
    int i = (blockIdx.x*256 + threadIdx.x)*4;
    float4 v = *(const float4*)(x + i);
    float vv[4] = {v.x, v.y, v.z, v.w};
    bf16x4 h, l;
#pragma unroll
    for(int j=0;j<4;j++){
        __bf16 hj = (__bf16)vv[j];
        h[j] = hj;
        l[j] = (__bf16)(vv[j] - (float)hj);
    }
    *(bf16x4*)(xh + i) = h;
    *(bf16x4*)(xl + i) = l;
}

// ---------------- prepass: W (fp32, [k][n]) -> WT (bf16, [n][k]), 4 gates ----------------
__global__ __launch_bounds__(256) void k_convert_w(const float* __restrict__ W0,
                                                   const float* __restrict__ W1,
                                                   const float* __restrict__ W2,
                                                   const float* __restrict__ W3,
                                                   __bf16* __restrict__ WT){
    __shared__ float t[32][33];
    int tx = threadIdx.x, ty = threadIdx.y;          // block (32,8)
    int n0 = blockIdx.x*32, k0 = blockIdx.y*32;
    int g = blockIdx.z;
    const float* W = (g==0)?W0:(g==1)?W1:(g==2)?W2:W3;
    __bf16* wt = WT + (size_t)g*DIM*DIM;
#pragma unroll
    for(int j=0;j<4;j++)
        t[ty + j*8][tx] = W[(size_t)(k0 + ty + j*8)*DIM + n0 + tx];
    __syncthreads();
#pragma unroll
    for(int j=0;j<4;j++)
        wt[(size_t)(n0 + ty + j*8)*DIM + k0 + tx] = (__bf16)t[tx][ty + j*8];
}

// ---------------- unified 4-gate GEMM ----------------
// Block computes 128(M) x 64(N) for ALL 4 gates. A (hi+lo) staged once per K-step.
// LDS layout (8 regions x 4 KiB): [0,1]=A_hi rows 0-63/64-127, [2,3]=A_lo, [4..7]=B gate 0..3.
// XOR swizzle: element (row r, k-seg q) lives at r*64 + (q ^ ((r>>1)&3))*16.
__global__ __launch_bounds__(256,2) void k_gemm(
        const __bf16* __restrict__ xh, const __bf16* __restrict__ xl,
        const __bf16* __restrict__ WT,            // [4][DIM][DIM], n-major
        const float* __restrict__ b0, const float* __restrict__ b1,
        const float* __restrict__ b2, const float* __restrict__ b3,
        __bf16* __restrict__ F, __bf16* __restrict__ INP, __bf16* __restrict__ G)
{
    __shared__ __bf16 smem[8*2048];   // 32 KiB
    const int tid = threadIdx.x;
    const int nb = blockIdx.x, mb = blockIdx.y;

    const __bf16* ah = xh + (size_t)mb*128*DIM;
    const __bf16* al = xl + (size_t)mb*128*DIM;

    const int lane = tid & 63, wv = tid >> 6;
    const int wm = wv & 1, wn = wv >> 1;          // waves: 2 row-halves x 2 col-halves
    const int quad = lane >> 4, l15 = lane & 15;

    f32x4 acc[4][4][2];
#pragma unroll
    for(int g=0;g<4;g++)
#pragma unroll
        for(int i=0;i<4;i++)
#pragma unroll
            for(int j=0;j<2;j++) acc[g][i][j] = (f32x4){0.f,0.f,0.f,0.f};

    // staging source mapping (undoes the XOR swizzle): thread t -> region row r=t>>2,
    // LDS slot t&3, global seg = (t&3) ^ ((r>>1)&3) = (t&3) ^ ((t>>3)&3)
    const int rA   = tid >> 2;
    const int sseg = ((tid & 3) ^ ((tid >> 3) & 3)) * 8;   // element offset
    char* lds_base = (char*)smem;

    const __bf16* pa0 = ah + (size_t)(rA     )*DIM + sseg;
    const __bf16* pa1 = ah + (size_t)(64 + rA)*DIM + sseg;
    const __bf16* pl0 = al + (size_t)(rA     )*DIM + sseg;
    const __bf16* pl1 = al + (size_t)(64 + rA)*DIM + sseg;
    const __bf16* pb[4];
#pragma unroll
    for(int g=0;g<4;g++)
        pb[g] = WT + (size_t)g*DIM*DIM + (size_t)(nb*64 + rA)*DIM + sseg;

    // fragment read offsets (bytes), swizzle-corrected; constant across i/j since
    // ((base + 16*i)>>1)&3 == (base>>1)&3
    const int rowA  = wm*64 + l15;
    const int offA  = (quad ^ ((rowA>>1)&3))*16;
    const int rowB  = wn*32 + l15;
    const int offB  = (quad ^ ((rowB>>1)&3))*16;

#pragma unroll 1
    for(int kt=0; kt<DIM/32; ++kt){
        const int k0 = kt*32;
        __syncthreads();
        __builtin_amdgcn_global_load_lds((const __attribute__((address_space(1))) void*)(pa0 + k0),
            (__attribute__((address_space(3))) void*)(lds_base + (0*256+tid)*16), 16, 0, 0);
        __builtin_amdgcn_global_load_lds((const __attribute__((address_space(1))) void*)(pa1 + k0),
            (__attribute__((address_space(3))) void*)(lds_base + (1*256+tid)*16), 16, 0, 0);
        __builtin_amdgcn_global_load_lds((const __attribute__((address_space(1))) void*)(pl0 + k0),
            (__attribute__((address_space(3))) void*)(lds_base + (2*256+tid)*16), 16, 0, 0);
        __builtin_amdgcn_global_load_lds((const __attribute__((address_space(1))) void*)(pl1 + k0),
            (__attribute__((address_space(3))) void*)(lds_base + (3*256+tid)*16), 16, 0, 0);
        __builtin_amdgcn_global_load_lds((const __attribute__((address_space(1))) void*)(pb[0] + k0),
            (__attribute__((address_space(3))) void*)(lds_base + (4*256+tid)*16), 16, 0, 0);
        __builtin_amdgcn_global_load_lds((const __attribute__((address_space(1))) void*)(pb[1] + k0),
            (__attribute__((address_space(3))) void*)(lds_base + (5*256+tid)*16), 16, 0, 0);
        __builtin_amdgcn_global_load_lds((const __attribute__((address_space(1))) void*)(pb[2] + k0),
            (__attribute__((address_space(3))) void*)(lds_base + (6*256+tid)*16), 16, 0, 0);
        __builtin_amdgcn_global_load_lds((const __attribute__((address_space(1))) void*)(pb[3] + k0),
            (__attribute__((address_space(3))) void*)(lds_base + (7*256+tid)*16), 16, 0, 0);
        __syncthreads();

        bf16x8 fh[4], fl[4];
#pragma unroll
        for(int i=0;i<4;i++){
            int rbyte = (rowA + i*16)*64 + offA;
            fh[i] = *(const bf16x8*)(lds_base + rbyte);
            fl[i] = *(const bf16x8*)(lds_base + 8192 + rbyte);
        }
#pragma unroll
        for(int g=0;g<4;g++){
            bf16x8 fb0 = *(const bf16x8*)(lds_base + 16384 + g*4096 + (rowB     )*64 + offB);
            bf16x8 fb1 = *(const bf16x8*)(lds_base + 16384 + g*4096 + (rowB + 16)*64 + offB);
#pragma unroll
            for(int i=0;i<4;i++){
                acc[g][i][0] = __builtin_amdgcn_mfma_f32_16x16x32_bf16(fh[i], fb0, acc[g][i][0], 0,0,0);
                acc[g][i][0] = __builtin_amdgcn_mfma_f32_16x16x32_bf16(fl[i], fb0, acc[g][i][0], 0,0,0);
                acc[g][i][1] = __builtin_amdgcn_mfma_f32_16x16x32_bf16(fh[i], fb1, acc[g][i][1], 0,0,0);
                acc[g][i][1] = __builtin_amdgcn_mfma_f32_16x16x32_bf16(fl[i], fb1, acc[g][i][1], 0,0,0);
            }
        }
    }

    // epilogue: f=sig, inp=tanh*sig, og=sig; bf16 stores
#pragma unroll
    for(int j=0;j<2;j++){
        int col = nb*64 + wn*32 + j*16 + l15;
        float bvf = b0[col], bvi = b1[col], bvg = b2[col], bvo = b3[col];
#pragma unroll
        for(int i=0;i<4;i++){
#pragma unroll
            for(int r=0;r<4;r++){
                int m = mb*128 + wm*64 + i*16 + quad*4 + r;
                size_t o = (size_t)m*DIM + col;
                F[o]   = (__bf16)sigmoid_f(acc[0][i][j][r] + bvf);
                float it = tanh_f   (acc[1][i][j][r] + bvi);
                float ig = sigmoid_f(acc[2][i][j][r] + bvg);
                INP[o] = (__bf16)(it*ig);
                G[o]   = (__bf16)sigmoid_f(acc[3][i][j][r] + bvo);
            }
        }
    }
}

// ---------------- scan pass 1: per-chunk (P = prod f, H = local scan from 0) ----------------
__global__ __launch_bounds__(256) void k_scan1(const __bf16* __restrict__ F, const __bf16* __restrict__ INP,
                                               float* __restrict__ P, float* __restrict__ Hc){
    int c = blockIdx.x, dblk = blockIdx.y, b = blockIdx.z;
    int d = (dblk*256 + threadIdx.x)*2;
    size_t base = ((size_t)(b*LSEQ + c*CLEN))*DIM + d;
    float p0=1.f,p1=1.f,h0=0.f,h1=0.f;
#pragma unroll 4
    for(int t=0;t<CLEN;t++){
        bf16x2 fv = *(const bf16x2*)(F   + base + (size_t)t*DIM);
        bf16x2 iv = *(const bf16x2*)(INP + base + (size_t)t*DIM);
        h0 = (float)fv[0]*h0 + (float)iv[0];
        h1 = (float)fv[1]*h1 + (float)iv[1];
        p0 *= (float)fv[0];
        p1 *= (float)fv[1];
    }
    int bd = b*DIM + d;
    *(float2*)(P  + c*(BSZ*DIM) + bd) = make_float2(p0,p1);
    *(float2*)(Hc + c*(BSZ*DIM) + bd) = make_float2(h0,h1);
}

// ---------------- scan pass 2: chunk-level scan, seeded with last_hidden_init ----------------
__global__ __launch_bounds__(256) void k_scan2(const float* __restrict__ P, const float* __restrict__ Hc,
                                               const float* __restrict__ lh, float* __restrict__ Hin){
    int bd = blockIdx.x*256 + threadIdx.x;   // 0..4095
    int d = bd & (DIM-1);
    float h = lh[d];
#pragma unroll
    for(int c=0;c<CHUNKS;c++){
        Hin[c*(BSZ*DIM) + bd] = h;
        h = P[c*(BSZ*DIM) + bd]*h + Hc[c*(BSZ*DIM) + bd];
    }
}

// ---------------- scan pass 3: replay chunks, fuse y = tanh(h)*G ----------------
__global__ __launch_bounds__(256) void k_scan3(const __bf16* __restrict__ F, const __bf16* __restrict__ INP,
                                               const __bf16* __restrict__ G, const float* __restrict__ Hin,
                                               float* __restrict__ Y){
    int c = blockIdx.x, dblk = blockIdx.y, b = blockIdx.z;
    int d = (dblk*256 + threadIdx.x)*2;
    int bd = b*DIM + d;
    size_t base = ((size_t)(b*LSEQ + c*CLEN))*DIM + d;
    float2 hv = *(const float2*)(Hin + c*(BSZ*DIM) + bd);
    float h0 = hv.x, h1 = hv.y;
#pragma unroll 4
    for(int t=0;t<CLEN;t++){
        size_t o = base + (size_t)t*DIM;
        bf16x2 fv = *(const bf16x2*)(F + o);
        bf16x2 iv = *(const bf16x2*)(INP + o);
        bf16x2 gv = *(const bf16x2*)(G + o);
        h0 = (float)fv[0]*h0 + (float)iv[0];
        h1 = (float)fv[1]*h1 + (float)iv[1];
        *(float2*)(Y + o) = make_float2(tanh_f(h0)*(float)gv[0], tanh_f(h1)*(float)gv[1]);
    }
}

extern "C" void kernel_launch(void* const* d_in, const int* in_sizes, int n_in,
                              void* d_out, int out_size, void* d_ws, size_t ws_size,
                              hipStream_t stream){
    const float* x  = (const float*)d_in[0];
    const float* W[4]    = {(const float*)d_in[1], (const float*)d_in[3],
                            (const float*)d_in[5], (const float*)d_in[7]};
    const float* bias[4] = {(const float*)d_in[2], (const float*)d_in[4],
                            (const float*)d_in[6], (const float*)d_in[8]};
    const float* lh = (const float*)d_in[9];
    float* Y = (float*)d_out;

    char* ws = (char*)d_ws;
    __bf16* xh = (__bf16*)(ws);                         //  64 MiB
    __bf16* xl = (__bf16*)(ws + ((size_t) 64<<20));     //  64 MiB
    __bf16* WT = (__bf16*)(ws + ((size_t)128<<20));     //   8 MiB
    __bf16* F  = (__bf16*)(ws + ((size_t)136<<20));     //  64 MiB
    __bf16* INP= (__bf16*)(ws + ((size_t)200<<20));     //  64 MiB
    __bf16* G  = (__bf16*)(ws + ((size_t)264<<20));     //  64 MiB
    float*  P  = (float*) (ws + ((size_t)328<<20));     //   1 MiB
    float*  Hc = (float*) (ws + ((size_t)329<<20));     //   1 MiB
    float*  Hin= (float*) (ws + ((size_t)330<<20));     //   1 MiB  (total 331 MiB)

    hipLaunchKernelGGL(k_convert_x, dim3(M_TOT*DIM/(4*256)), dim3(256), 0, stream, x, xh, xl);
    hipLaunchKernelGGL(k_convert_w, dim3(32,32,4), dim3(32,8), 0, stream,
                       W[0], W[1], W[2], W[3], WT);
    hipLaunchKernelGGL(k_gemm, dim3(16, M_TOT/128), dim3(256), 0, stream,
                       xh, xl, WT, bias[0], bias[1], bias[2], bias[3], F, INP, G);
    hipLaunchKernelGGL(k_scan1, dim3(CHUNKS, DIM/512, BSZ), dim3(256), 0, stream, F, INP, P, Hc);
    hipLaunchKernelGGL(k_scan2, dim3(BSZ*DIM/256), dim3(256), 0, stream, P, Hc, lh, Hin);
    hipLaunchKernelGGL(k_scan3, dim3(CHUNKS, DIM/512, BSZ), dim3(256), 0, stream, F, INP, G, Hin, Y);
}